// Round 8
// baseline (306.808 us; speedup 1.0000x reference)
//
#include <hip/hip_runtime.h>

#define N_NODES 50000
#define N_EDGES 300000
#define N_TOT   350000   // edges + self-loops
#define D       256
#define MPAD    50048    // N_NODES padded; multiple of 128
#define SCAN_B  196      // ceil(50000/256)
#define TILE    64       // agg node-tile
#define AGRID   (MPAD / TILE * 8)   // 782 tiles x 8 column-groups = 6256
#define GEMM_B  784      // 8 XCDs x 98 slots (covers 391 M-tiles x 2 N-halves)
#define EMAX    896      // LDS edge-slice capacity (mean 448, sd ~21)

typedef __attribute__((ext_vector_type(8))) short bf16x8;
typedef __attribute__((ext_vector_type(4))) float f32x4;
typedef __attribute__((ext_vector_type(8))) unsigned short u16x8;
typedef __attribute__((ext_vector_type(4))) unsigned short u16x4;

__device__ __forceinline__ float bf2f(unsigned short b) {
    union { unsigned u; float f; } v; v.u = ((unsigned)b) << 16; return v.f;
}
__device__ __forceinline__ unsigned short f2bf(float f) {
    union { float f; unsigned u; } v; v.f = f;
    unsigned u = v.u;
    unsigned r = (u + 0x7FFFu + ((u >> 16) & 1u)) >> 16;   // round-nearest-even
    return (unsigned short)r;
}
__device__ __forceinline__ void g2lds16(const unsigned short* g, unsigned short* l) {
    __builtin_amdgcn_global_load_lds(
        (const __attribute__((address_space(1))) void*)g,
        (__attribute__((address_space(3))) void*)l, 16, 0, 0);
}

// ---- k1: hist + W-transpose + embed, all independent, grid = MPAD/8 = 6256 ----
__global__ __launch_bounds__(256) void k1_kernel(
        const float* __restrict__ x, const int* __restrict__ ei,
        const float* __restrict__ We, const float* __restrict__ be,
        const float* __restrict__ W1, const float* __restrict__ W2,
        int* __restrict__ cnt,
        unsigned short* __restrict__ Wt1, unsigned short* __restrict__ Wt2,
        unsigned short* __restrict__ hA) {
    int t = threadIdx.x, b = blockIdx.x;
    int tid = b * 256 + t;

    // histogram over dst (cnt pre-zeroed by memset)
    if (tid < N_TOT) {
        int dst = (tid < N_EDGES) ? ei[N_EDGES + tid] : (tid - N_EDGES);
        atomicAdd(&cnt[dst], 1);
    }
    // transpose + cast weights (first 512 blocks, 1 elem/thread)
    if (tid < 2 * D * D) {
        int wsel = tid >> 16, rem = tid & 65535;
        int tt = rem >> 8, bb = rem & 255;             // coalesced over bb
        const float* W = wsel ? W2 : W1;
        unsigned short* Wt = wsel ? Wt2 : Wt1;
        Wt[bb * D + tt] = f2bf(W[tt * D + bb]);
    }
    // embed: block b -> nodes b*8 .. b*8+7 (pad rows get 0)
    float w[11];
    #pragma unroll
    for (int k = 0; k < 11; ++k) w[k] = We[k * D + t];
    float bb = be[t];
    #pragma unroll
    for (int ni = 0; ni < 8; ++ni) {
        int node = b * 8 + ni;
        float acc = 0.f;
        if (node < N_NODES) {
            acc = bb;
            #pragma unroll
            for (int k = 0; k < 11; ++k) acc += x[node * 11 + k] * w[k];
            acc = fmaxf(acc, 0.f);
        }
        hA[(size_t)node * D + t] = f2bf(acc);
    }
}

// ---- k2: standalone scan (decoupled single-pass, 196 blocks) ----
__global__ __launch_bounds__(256) void k2_kernel(const int* __restrict__ cnt,
                                                 float* __restrict__ dis,
                                                 int* __restrict__ locs,
                                                 int* __restrict__ bsum,
                                                 int* __restrict__ done) {
    __shared__ int ws[4];
    __shared__ int amLast;
    int t = threadIdx.x;
    int lane = t & 63, wv4 = t >> 6;
    int i = blockIdx.x * 256 + t;
    int v = (i < N_NODES) ? cnt[i] : 0;
    if (i < N_NODES) dis[i] = rsqrtf((float)v);    // deg >= 1 (self-loop)
    int s = v;
    #pragma unroll
    for (int d = 1; d < 64; d <<= 1) {
        int u = __shfl_up(s, d, 64);
        if (lane >= d) s += u;
    }
    if (lane == 63) ws[wv4] = s;
    __syncthreads();
    int off = 0;
    #pragma unroll
    for (int k = 0; k < 4; ++k) if (k < wv4) off += ws[k];
    s += off;
    if (i < N_NODES) locs[i] = s;                  // inclusive local scan
    if (t == 255) {
        bsum[blockIdx.x] = s;
        __threadfence();
        amLast = (atomicAdd(done, 1) == SCAN_B - 1);
    }
    __syncthreads();
    if (amLast) {
        __threadfence();
        int vv = 0;
        if (t < SCAN_B)
            vv = __hip_atomic_load(&bsum[t], __ATOMIC_RELAXED, __HIP_MEMORY_SCOPE_AGENT);
        int ss = vv;
        #pragma unroll
        for (int d = 1; d < 64; d <<= 1) {
            int u = __shfl_up(ss, d, 64);
            if (lane >= d) ss += u;
        }
        __syncthreads();                           // ws reuse
        if (lane == 63) ws[wv4] = ss;
        __syncthreads();
        int off2 = 0;
        #pragma unroll
        for (int k = 0; k < 4; ++k) if (k < wv4) off2 += ws[k];
        ss += off2;
        if (t < SCAN_B) bsum[t] = ss - vv;         // exclusive block offsets
    }
}

// ---- k3: rowptr materialization + CSR fill (u16 src only; norms come from dis) ----
__global__ __launch_bounds__(256) void k3_kernel(const int* __restrict__ ei,
                          const int* __restrict__ locs,
                          const int* __restrict__ bsum,
                          int* __restrict__ fc, int* __restrict__ rowptr,
                          unsigned short* __restrict__ esrc) {
    int tid = blockIdx.x * 256 + threadIdx.x;
    if (tid == 0) rowptr[0] = 0;
    if (tid < N_NODES)
        rowptr[tid + 1] = locs[tid] + bsum[tid >> 8];
    if (tid < N_TOT) {
        int src, dst;
        if (tid < N_EDGES) { src = ei[tid]; dst = ei[N_EDGES + tid]; }
        else               { src = dst = tid - N_EDGES; }
        int base = bsum[dst >> 8] + ((dst & 255) ? locs[dst - 1] : 0);
        int pos = base + atomicAdd(&fc[dst], 1);
        esrc[pos] = (unsigned short)src;           // N_NODES < 65536
    }
}

// ---- aggk: column-sliced aggregation, gA[n][:] = sum_e norm * hw[src][:].
// Block bid: column-group cg = bid&7 (32 cols, 64B/row), tile = bid>>3.
// Under round-robin dispatch all blocks on XCD c touch only slice c
// (3.2MB, fits 4MB per-XCD L2) -> gather becomes L2-HIT; table fetched
// from HBM once (25.6MB total) instead of ~77MB MSHR-bound (v3 lesson:
// occupancy 2.4x gave 0% -> miss-path throughput was the wall, cut misses).
// Half-wave (32 lanes) per node: 4 edge-groups x 8 lanes x 8B = 4 edges/step,
// 2 steps issued back-to-back (8 edges in flight); reduce over groups via
// shfl_xor 8/16. Norms: dis[src]*dis[node], dis L2-resident (200KB). ----
__global__ __launch_bounds__(256) void aggk(
        const unsigned short* __restrict__ hw,
        const int* __restrict__ rowptr,
        const unsigned short* __restrict__ esrc,
        const float* __restrict__ dis,
        unsigned short* __restrict__ gA) {
    __shared__ unsigned short sL[EMAX];
    __shared__ int rL[TILE + 1];
    int t = threadIdx.x, bid = blockIdx.x;
    int cg = bid & 7, tile = bid >> 3;
    int m0 = tile * TILE;
    int mEnd = m0 + TILE; if (mEnd > N_NODES) mEnd = N_NODES;

    int s0b = rowptr[m0], s1b = rowptr[mEnd];
    int nE = s1b - s0b;
    bool useL = (nE <= EMAX);                      // block-uniform
    if (t <= TILE) {
        int idx = m0 + t;
        rL[t] = rowptr[idx > N_NODES ? N_NODES : idx];
    }
    if (useL)
        for (int i = t; i < nE; i += 256) sL[i] = esrc[s0b + i];
    __syncthreads();

    int wid = t >> 6, lane = t & 63;
    int h = lane >> 5, hl = lane & 31;
    int hw8 = wid * 2 + h;                         // half-wave id 0..7
    int g = hl >> 3, c = hl & 7;                   // edge-group, col-octet
    const unsigned short* tb = hw + cg * 32 + c * 4;

    for (int j = 0; j < 8; ++j) {                  // 8 nodes per half-wave
        int nn = hw8 * 8 + j;
        int node = m0 + nn;
        int s0 = rL[nn], deg = rL[nn + 1] - s0;
        int ls0 = s0 - s0b;
        float disD = (deg > 0) ? dis[node] : 0.f;  // deg==0 only for pad rows
        float a0 = 0.f, a1 = 0.f, a2 = 0.f, a3 = 0.f;
        for (int off = 0; off < deg; off += 8) {
            int i1 = off + g, i2 = off + 4 + g;
            int src1 = 0, src2 = 0; float n1 = 0.f, n2 = 0.f;
            if (i1 < deg) {
                src1 = useL ? sL[ls0 + i1] : esrc[s0 + i1];
                n1 = dis[src1] * disD;
            }
            if (i2 < deg) {
                src2 = useL ? sL[ls0 + i2] : esrc[s0 + i2];
                n2 = dis[src2] * disD;
            }
            u16x4 r1 = *(const u16x4*)(tb + (size_t)src1 * D);
            u16x4 r2 = *(const u16x4*)(tb + (size_t)src2 * D);
            a0 += n1 * bf2f(r1[0]); a1 += n1 * bf2f(r1[1]);
            a2 += n1 * bf2f(r1[2]); a3 += n1 * bf2f(r1[3]);
            a0 += n2 * bf2f(r2[0]); a1 += n2 * bf2f(r2[1]);
            a2 += n2 * bf2f(r2[2]); a3 += n2 * bf2f(r2[3]);
        }
        // reduce over the 4 edge-groups (xor 8,16 stays within each half)
        a0 += __shfl_xor(a0, 8, 64);  a1 += __shfl_xor(a1, 8, 64);
        a2 += __shfl_xor(a2, 8, 64);  a3 += __shfl_xor(a3, 8, 64);
        a0 += __shfl_xor(a0, 16, 64); a1 += __shfl_xor(a1, 16, 64);
        a2 += __shfl_xor(a2, 16, 64); a3 += __shfl_xor(a3, 16, 64);
        if (hl < 8) {                              // lanes c=hl, g=0 write 64B
            u16x4 o = { f2bf(a0), f2bf(a1), f2bf(a2), f2bf(a3) };
            *(u16x4*)(gA + (size_t)node * D + cg * 32 + hl * 4) = o;
        }
    }
}

// ---- GEMM (round-2 verified): BK=64, XOR-swizzled LDS, XCD-paired 1-D grid,
// swapped-operand MFMA, fused bias (+relu->bf16 | ->f32 guarded) epilogue ----
__global__ __launch_bounds__(256) void gemm_kernel(const unsigned short* __restrict__ A,
                                                   const unsigned short* __restrict__ Bt,
                                                   const float* __restrict__ bias,
                                                   unsigned short* __restrict__ Cb,
                                                   float* __restrict__ Cf,
                                                   int mode) {
    __shared__ unsigned short lA[128 * 64];   // 16KB
    __shared__ unsigned short lB[128 * 64];   // 16KB
    int t = threadIdx.x;
    int bid = blockIdx.x;

    int xcd = bid & 7, s = bid >> 3;
    int pair = xcd * 49 + (s >> 1);           // M-tile
    int ny   = s & 1;                         // N-half
    if (pair >= MPAD / 128) return;

    int wv = t >> 6, lane = t & 63;
    int m0 = pair * 128;
    int n0 = ny * 128;
    int moff = (wv & 1) * 64, noff = (wv >> 1) * 64;
    int q = lane >> 4, r = lane & 15;

    int srow[4], scol[4];
    #pragma unroll
    for (int j = 0; j < 4; ++j) {
        int idx = j * 256 + t;
        srow[j] = idx >> 3;
        scol[j] = ((idx & 7) ^ (srow[j] & 7)) * 8;
    }

    f32x4 acc[4][4] = {};
    for (int kk = 0; kk < D; kk += 64) {
        __syncthreads();
        #pragma unroll
        for (int j = 0; j < 4; ++j) {
            int idx = j * 256 + t;
            g2lds16(A  + (size_t)(m0 + srow[j]) * D + kk + scol[j], lA + idx * 8);
            g2lds16(Bt + (size_t)(n0 + srow[j]) * D + kk + scol[j], lB + idx * 8);
        }
        __syncthreads();
        #pragma unroll
        for (int ks = 0; ks < 2; ++ks) {
            bf16x8 a[4], b[4];
            #pragma unroll
            for (int mt = 0; mt < 4; ++mt) {
                int row = moff + mt * 16 + r;
                a[mt] = *(const bf16x8*)(lA + row * 64 + (((ks * 4 + q) ^ (r & 7)) * 8));
            }
            #pragma unroll
            for (int nt = 0; nt < 4; ++nt) {
                int row = noff + nt * 16 + r;
                b[nt] = *(const bf16x8*)(lB + row * 64 + (((ks * 4 + q) ^ (r & 7)) * 8));
            }
            #pragma unroll
            for (int mt = 0; mt < 4; ++mt)
                #pragma unroll
                for (int nt = 0; nt < 4; ++nt)
                    acc[mt][nt] = __builtin_amdgcn_mfma_f32_16x16x32_bf16(b[nt], a[mt], acc[mt][nt], 0, 0, 0);
        }
    }
    #pragma unroll
    for (int mt = 0; mt < 4; ++mt) {
        int mrow = m0 + moff + mt * 16 + r;
        #pragma unroll
        for (int nt = 0; nt < 4; ++nt) {
            int ncol = n0 + noff + nt * 16 + (q << 2);
            float4 bv = *(const float4*)(bias + ncol);
            float v[4] = { acc[mt][nt][0] + bv.x, acc[mt][nt][1] + bv.y,
                           acc[mt][nt][2] + bv.z, acc[mt][nt][3] + bv.w };
            if (mode) {
                u16x4 o;
                #pragma unroll
                for (int i = 0; i < 4; ++i) o[i] = f2bf(fmaxf(v[i], 0.f));
                *(u16x4*)(Cb + (size_t)mrow * D + ncol) = o;
            } else if (mrow < N_NODES) {
                float4 o = { v[0], v[1], v[2], v[3] };
                *(float4*)(Cf + (size_t)mrow * D + ncol) = o;
            }
        }
    }
}

extern "C" void kernel_launch(void* const* d_in, const int* in_sizes, int n_in,
                              void* d_out, int out_size, void* d_ws, size_t ws_size,
                              hipStream_t stream) {
    const float* x  = (const float*)d_in[0];
    const int*   ei = (const int*)d_in[1];
    const float* We = (const float*)d_in[2];
    const float* be = (const float*)d_in[3];
    const float* W1 = (const float*)d_in[4];
    const float* b1 = (const float*)d_in[5];
    const float* W2 = (const float*)d_in[6];
    const float* b2 = (const float*)d_in[7];
    float* out = (float*)d_out;

    char* w = (char*)d_ws;
    auto alloc = [&](size_t bytes) {
        char* p = w;
        w += (bytes + 255) & ~(size_t)255;
        return p;
    };
    // cnt, fc, done contiguous -> single memset covers all three
    int*            cnt    = (int*)alloc((size_t)N_NODES * 4);
    int*            fc     = (int*)alloc((size_t)N_NODES * 4);
    int*            done   = (int*)alloc(4);
    size_t zero_span = (size_t)((char*)(done + 64) - (char*)cnt);
    int*            rowptr = (int*)alloc((size_t)(N_NODES + 1) * 4);
    int*            locs   = (int*)alloc((size_t)N_NODES * 4);
    int*            bsum   = (int*)alloc((size_t)SCAN_B * 4);
    float*          dis    = (float*)alloc((size_t)N_NODES * 4);
    unsigned short* esrc   = (unsigned short*)alloc((size_t)N_TOT * 2);
    unsigned short* Wt1    = (unsigned short*)alloc((size_t)D * D * 2);
    unsigned short* Wt2    = (unsigned short*)alloc((size_t)D * D * 2);
    unsigned short* hA     = (unsigned short*)alloc((size_t)MPAD * D * 2);
    unsigned short* h1     = (unsigned short*)alloc((size_t)MPAD * D * 2);
    unsigned short* gA     = (unsigned short*)alloc((size_t)MPAD * D * 2);

    hipMemsetAsync(cnt, 0, zero_span, stream);
    k1_kernel<<<MPAD / 8, 256, 0, stream>>>(x, ei, We, be, W1, W2, cnt, Wt1, Wt2, hA);
    k2_kernel<<<SCAN_B, 256, 0, stream>>>(cnt, dis, locs, bsum, done);
    k3_kernel<<<(N_TOT + 255) / 256, 256, 0, stream>>>(ei, locs, bsum, fc,
                                                       rowptr, esrc);
    // layer 1: gA = Agg(hA); h1 = relu(gA*W1 + b1)
    aggk<<<AGRID, 256, 0, stream>>>(hA, rowptr, esrc, dis, gA);
    gemm_kernel<<<GEMM_B, 256, 0, stream>>>(gA, Wt1, b1, h1, nullptr, 1);
    // layer 2: gA = Agg(h1); out = gA*W2 + b2
    aggk<<<AGRID, 256, 0, stream>>>(h1, rowptr, esrc, dis, gA);
    gemm_kernel<<<GEMM_B, 256, 0, stream>>>(gA, Wt2, b2, nullptr, out, 0);
}

// Round 9
// 264.724 us; speedup vs baseline: 1.1590x; 1.1590x over previous
//
#include <hip/hip_runtime.h>

#define N_NODES 50000
#define N_EDGES 300000
#define N_TOT   350000   // edges + self-loops
#define D       256
#define MPAD    50048    // N_NODES padded; multiple of 128
#define SCAN_B  196      // ceil(50000/256)
#define GEMM_B  784      // 8 XCDs x 98 slots (covers 391 M-tiles x 2 N-halves)

typedef __attribute__((ext_vector_type(8))) short bf16x8;
typedef __attribute__((ext_vector_type(4))) float f32x4;
typedef __attribute__((ext_vector_type(8))) unsigned short u16x8;
typedef __attribute__((ext_vector_type(4))) unsigned short u16x4;

__device__ __forceinline__ float bf2f(unsigned short b) {
    union { unsigned u; float f; } v; v.u = ((unsigned)b) << 16; return v.f;
}
__device__ __forceinline__ unsigned short f2bf(float f) {
    union { float f; unsigned u; } v; v.f = f;
    unsigned u = v.u;
    unsigned r = (u + 0x7FFFu + ((u >> 16) & 1u)) >> 16;   // round-nearest-even
    return (unsigned short)r;
}
__device__ __forceinline__ void g2lds16(const unsigned short* g, unsigned short* l) {
    __builtin_amdgcn_global_load_lds(
        (const __attribute__((address_space(1))) void*)g,
        (__attribute__((address_space(3))) void*)l, 16, 0, 0);
}

// ---- k1: histogram + W-transpose (embed ELIMINATED - recomputed in agg1r) ----
__global__ __launch_bounds__(256) void k1_kernel(
        const int* __restrict__ ei,
        const float* __restrict__ W1, const float* __restrict__ W2,
        int* __restrict__ cnt,
        unsigned short* __restrict__ Wt1, unsigned short* __restrict__ Wt2) {
    int tid = blockIdx.x * 256 + threadIdx.x;
    // histogram over dst (cnt pre-zeroed by memset)
    if (tid < N_TOT) {
        int dst = (tid < N_EDGES) ? ei[N_EDGES + tid] : (tid - N_EDGES);
        atomicAdd(&cnt[dst], 1);
    }
    // transpose + cast weights (1 elem/thread over first 512 blocks)
    if (tid < 2 * D * D) {
        int wsel = tid >> 16, rem = tid & 65535;
        int tt = rem >> 8, bb = rem & 255;             // coalesced over bb
        const float* W = wsel ? W2 : W1;
        unsigned short* Wt = wsel ? Wt2 : Wt1;
        Wt[bb * D + tt] = f2bf(W[tt * D + bb]);
    }
}

// ---- k2: standalone scan (decoupled single-pass, 196 blocks; r6-verified) ----
__global__ __launch_bounds__(256) void k2_kernel(const int* __restrict__ cnt,
                                                 float* __restrict__ dis,
                                                 int* __restrict__ locs,
                                                 int* __restrict__ bsum,
                                                 int* __restrict__ done) {
    __shared__ int ws[4];
    __shared__ int amLast;
    int t = threadIdx.x;
    int lane = t & 63, wv4 = t >> 6;
    int i = blockIdx.x * 256 + t;
    int v = (i < N_NODES) ? cnt[i] : 0;
    if (i < N_NODES) dis[i] = rsqrtf((float)v);    // deg >= 1 (self-loop)
    int s = v;
    #pragma unroll
    for (int d = 1; d < 64; d <<= 1) {
        int u = __shfl_up(s, d, 64);
        if (lane >= d) s += u;
    }
    if (lane == 63) ws[wv4] = s;
    __syncthreads();
    int off = 0;
    #pragma unroll
    for (int k = 0; k < 4; ++k) if (k < wv4) off += ws[k];
    s += off;
    if (i < N_NODES) locs[i] = s;                  // inclusive local scan
    if (t == 255) {
        bsum[blockIdx.x] = s;
        __threadfence();
        amLast = (atomicAdd(done, 1) == SCAN_B - 1);
    }
    __syncthreads();
    if (amLast) {
        __threadfence();
        int vv = 0;
        if (t < SCAN_B)
            vv = __hip_atomic_load(&bsum[t], __ATOMIC_RELAXED, __HIP_MEMORY_SCOPE_AGENT);
        int ss = vv;
        #pragma unroll
        for (int d = 1; d < 64; d <<= 1) {
            int u = __shfl_up(ss, d, 64);
            if (lane >= d) ss += u;
        }
        __syncthreads();                           // ws reuse
        if (lane == 63) ws[wv4] = ss;
        __syncthreads();
        int off2 = 0;
        #pragma unroll
        for (int k = 0; k < 4; ++k) if (k < wv4) off2 += ws[k];
        ss += off2;
        if (t < SCAN_B) bsum[t] = ss - vv;         // exclusive block offsets
    }
}

// ---- k3: rowptr materialization + CSR fill (packed src+norm int2; r2-verified) ----
__global__ __launch_bounds__(256) void k3_kernel(const int* __restrict__ ei,
                          const int* __restrict__ locs,
                          const int* __restrict__ bsum, const float* __restrict__ dis,
                          int* __restrict__ fc, int* __restrict__ rowptr,
                          int2* __restrict__ epk) {
    int tid = blockIdx.x * 256 + threadIdx.x;
    if (tid == 0) rowptr[0] = 0;
    if (tid < N_NODES)
        rowptr[tid + 1] = locs[tid] + bsum[tid >> 8];
    if (tid < N_TOT) {
        int src, dst;
        if (tid < N_EDGES) { src = ei[tid]; dst = ei[N_EDGES + tid]; }
        else               { src = dst = tid - N_EDGES; }
        int base = bsum[dst >> 8] + ((dst & 255) ? locs[dst - 1] : 0);
        int pos = base + atomicAdd(&fc[dst], 1);
        epk[pos] = make_int2(src, __float_as_int(dis[src] * dis[dst]));
    }
}

// ---- agg1r: g[dst] = sum_e norm_e * relu(x[src_e]*We + be)  (layer-1 agg,
// embed RECOMPUTED per edge). Rationale: rounds 4-8 proved the random 512B
// row-gather pins at ~1.7 TB/s L2-miss path regardless of occupancy/slicing;
// x is only 11-dim (2.2MB table -> L2-resident per XCD) so recompute turns
// 179MB of gather-wall traffic into ~2GF of VALU (~20us). Wave per node;
// lane owns 4 dims (We 44 regs); x-row read via readfirstlane -> s_load. ----
__global__ __launch_bounds__(256) void agg1r_kernel(
        const float* __restrict__ x,
        const float* __restrict__ We, const float* __restrict__ be,
        const int* __restrict__ rowptr, const int2* __restrict__ epk,
        unsigned short* __restrict__ g) {
    int wid = threadIdx.x >> 6, lane = threadIdx.x & 63;
    int node = blockIdx.x * 4 + wid;
    if (node >= MPAD) return;
    int d0 = lane * 4;
    float w[11][4];
    #pragma unroll
    for (int k = 0; k < 11; ++k) {
        float4 wv = *(const float4*)(We + k * D + d0);
        w[k][0] = wv.x; w[k][1] = wv.y; w[k][2] = wv.z; w[k][3] = wv.w;
    }
    float4 bev = *(const float4*)(be + d0);
    float acc[4] = {};
    if (node < N_NODES) {
        int s0 = rowptr[node], s1 = rowptr[node + 1];
        for (int base = s0; base < s1; base += 64) {
            int ec = s1 - base; if (ec > 64) ec = 64;
            int srcl = 0; float nml = 0.f;
            if (lane < ec) {
                int2 ep = epk[base + lane];
                srcl = ep.x; nml = __int_as_float(ep.y);
            }
            #pragma unroll 2
            for (int e = 0; e < ec; ++e) {
                int s = __builtin_amdgcn_readfirstlane(__shfl(srcl, e, 64));
                float n = __shfl(nml, e, 64);
                const float* xr = x + (size_t)s * 11;
                float z0 = bev.x, z1 = bev.y, z2 = bev.z, z3 = bev.w;
                #pragma unroll
                for (int k = 0; k < 11; ++k) {
                    float xv = xr[k];
                    z0 += xv * w[k][0]; z1 += xv * w[k][1];
                    z2 += xv * w[k][2]; z3 += xv * w[k][3];
                }
                acc[0] += n * fmaxf(z0, 0.f); acc[1] += n * fmaxf(z1, 0.f);
                acc[2] += n * fmaxf(z2, 0.f); acc[3] += n * fmaxf(z3, 0.f);
            }
        }
    }
    u16x4 o = { f2bf(acc[0]), f2bf(acc[1]), f2bf(acc[2]), f2bf(acc[3]) };
    *(u16x4*)(g + (size_t)node * D + d0) = o;    // pad rows get zeros
}

// ---- agg2: g[dst] = sum_e norm * h1[src]  (layer-2 gather; r2-verified v7
// structure: wave/node, 8 edges in flight via half-waves, full 512B rows).
// Output plain bf16 (bias/relu live in the following GEMM epilogue). ----
__global__ __launch_bounds__(256) void agg2_kernel(
        const unsigned short* __restrict__ hw,
        const int* __restrict__ rowptr,
        const int2* __restrict__ epk,
        unsigned short* __restrict__ out_bf) {
    int wid  = threadIdx.x >> 6;
    int lane = threadIdx.x & 63;
    int node = blockIdx.x * 4 + wid;
    if (node >= N_NODES) return;
    int s0 = rowptr[node], s1 = rowptr[node + 1];
    int half = lane >> 5, hl = lane & 31;

    float acc[8] = {};
    for (int base = s0; base < s1; base += 64) {   // one trip in practice
        int ec = s1 - base; if (ec > 64) ec = 64;
        int srcl = 0; float nml = 0.f;
        if (lane < ec) {
            int2 ep = epk[base + lane];
            srcl = ep.x; nml = __int_as_float(ep.y);
        }
        int it = (ec + 1) >> 1;                    // #trips (2 edges each)
        for (int i = 0; i < it; i += 4) {          // chunk = 8 edges in flight
            int   e0 = (2 * i + half) & 63;
            int   e1 = (2 * i + 2 + half) & 63;
            int   e2 = (2 * i + 4 + half) & 63;
            int   e3 = (2 * i + 6 + half) & 63;
            int   sa = __shfl(srcl, e0, 64);
            float na = __shfl(nml,  e0, 64);
            int   sb = __shfl(srcl, e1, 64);
            float nb = __shfl(nml,  e1, 64);
            int   sc = __shfl(srcl, e2, 64);
            float nc = __shfl(nml,  e2, 64);
            int   sd = __shfl(srcl, e3, 64);
            float nd = __shfl(nml,  e3, 64);       // zero-norm past end of row
            u16x8 ha = *(const u16x8*)(hw + (size_t)sa * D + hl * 8);
            u16x8 hb = *(const u16x8*)(hw + (size_t)sb * D + hl * 8);
            u16x8 hc = *(const u16x8*)(hw + (size_t)sc * D + hl * 8);
            u16x8 hd = *(const u16x8*)(hw + (size_t)sd * D + hl * 8);
            #pragma unroll
            for (int k = 0; k < 8; ++k) acc[k] += na * bf2f(ha[k]);
            #pragma unroll
            for (int k = 0; k < 8; ++k) acc[k] += nb * bf2f(hb[k]);
            #pragma unroll
            for (int k = 0; k < 8; ++k) acc[k] += nc * bf2f(hc[k]);
            #pragma unroll
            for (int k = 0; k < 8; ++k) acc[k] += nd * bf2f(hd[k]);
        }
    }
    #pragma unroll
    for (int k = 0; k < 8; ++k) acc[k] += __shfl_xor(acc[k], 32, 64);

    if (lane < 32) {
        int c = hl * 8;
        u16x8 ov;
        #pragma unroll
        for (int k = 0; k < 8; ++k) ov[k] = f2bf(acc[k]);
        *(u16x8*)(out_bf + (size_t)node * D + c) = ov;
    }
}

// ---- GEMM (r8-verified both modes): BK=64, XOR-swizzled LDS, XCD-paired 1-D
// grid, swapped-operand MFMA, fused bias (+relu->bf16 | ->f32 guarded) ----
__global__ __launch_bounds__(256) void gemm_kernel(const unsigned short* __restrict__ A,
                                                   const unsigned short* __restrict__ Bt,
                                                   const float* __restrict__ bias,
                                                   unsigned short* __restrict__ Cb,
                                                   float* __restrict__ Cf,
                                                   int mode) {
    __shared__ unsigned short lA[128 * 64];   // 16KB
    __shared__ unsigned short lB[128 * 64];   // 16KB
    int t = threadIdx.x;
    int bid = blockIdx.x;

    int xcd = bid & 7, s = bid >> 3;
    int pair = xcd * 49 + (s >> 1);           // M-tile
    int ny   = s & 1;                         // N-half
    if (pair >= MPAD / 128) return;

    int wv = t >> 6, lane = t & 63;
    int m0 = pair * 128;
    int n0 = ny * 128;
    int moff = (wv & 1) * 64, noff = (wv >> 1) * 64;
    int q = lane >> 4, r = lane & 15;

    int srow[4], scol[4];
    #pragma unroll
    for (int j = 0; j < 4; ++j) {
        int idx = j * 256 + t;
        srow[j] = idx >> 3;
        scol[j] = ((idx & 7) ^ (srow[j] & 7)) * 8;
    }

    f32x4 acc[4][4] = {};
    for (int kk = 0; kk < D; kk += 64) {
        __syncthreads();
        #pragma unroll
        for (int j = 0; j < 4; ++j) {
            int idx = j * 256 + t;
            g2lds16(A  + (size_t)(m0 + srow[j]) * D + kk + scol[j], lA + idx * 8);
            g2lds16(Bt + (size_t)(n0 + srow[j]) * D + kk + scol[j], lB + idx * 8);
        }
        __syncthreads();
        #pragma unroll
        for (int ks = 0; ks < 2; ++ks) {
            bf16x8 a[4], b[4];
            #pragma unroll
            for (int mt = 0; mt < 4; ++mt) {
                int row = moff + mt * 16 + r;
                a[mt] = *(const bf16x8*)(lA + row * 64 + (((ks * 4 + q) ^ (r & 7)) * 8));
            }
            #pragma unroll
            for (int nt = 0; nt < 4; ++nt) {
                int row = noff + nt * 16 + r;
                b[nt] = *(const bf16x8*)(lB + row * 64 + (((ks * 4 + q) ^ (r & 7)) * 8));
            }
            #pragma unroll
            for (int mt = 0; mt < 4; ++mt)
                #pragma unroll
                for (int nt = 0; nt < 4; ++nt)
                    acc[mt][nt] = __builtin_amdgcn_mfma_f32_16x16x32_bf16(b[nt], a[mt], acc[mt][nt], 0, 0, 0);
        }
    }
    #pragma unroll
    for (int mt = 0; mt < 4; ++mt) {
        int mrow = m0 + moff + mt * 16 + r;
        #pragma unroll
        for (int nt = 0; nt < 4; ++nt) {
            int ncol = n0 + noff + nt * 16 + (q << 2);
            float4 bv = *(const float4*)(bias + ncol);
            float v[4] = { acc[mt][nt][0] + bv.x, acc[mt][nt][1] + bv.y,
                           acc[mt][nt][2] + bv.z, acc[mt][nt][3] + bv.w };
            if (mode) {
                u16x4 o;
                #pragma unroll
                for (int i = 0; i < 4; ++i) o[i] = f2bf(fmaxf(v[i], 0.f));
                *(u16x4*)(Cb + (size_t)mrow * D + ncol) = o;
            } else if (mrow < N_NODES) {
                float4 o = { v[0], v[1], v[2], v[3] };
                *(float4*)(Cf + (size_t)mrow * D + ncol) = o;
            }
        }
    }
}

extern "C" void kernel_launch(void* const* d_in, const int* in_sizes, int n_in,
                              void* d_out, int out_size, void* d_ws, size_t ws_size,
                              hipStream_t stream) {
    const float* x  = (const float*)d_in[0];
    const int*   ei = (const int*)d_in[1];
    const float* We = (const float*)d_in[2];
    const float* be = (const float*)d_in[3];
    const float* W1 = (const float*)d_in[4];
    const float* b1 = (const float*)d_in[5];
    const float* W2 = (const float*)d_in[6];
    const float* b2 = (const float*)d_in[7];
    float* out = (float*)d_out;

    char* w = (char*)d_ws;
    auto alloc = [&](size_t bytes) {
        char* p = w;
        w += (bytes + 255) & ~(size_t)255;
        return p;
    };
    // cnt, fc, done contiguous -> single memset covers all three
    int*            cnt    = (int*)alloc((size_t)N_NODES * 4);
    int*            fc     = (int*)alloc((size_t)N_NODES * 4);
    int*            done   = (int*)alloc(4);
    size_t zero_span = (size_t)((char*)(done + 64) - (char*)cnt);
    int*            rowptr = (int*)alloc((size_t)(N_NODES + 1) * 4);
    int*            locs   = (int*)alloc((size_t)N_NODES * 4);
    int*            bsum   = (int*)alloc((size_t)SCAN_B * 4);
    float*          dis    = (float*)alloc((size_t)N_NODES * 4);
    int2*           epk    = (int2*)alloc((size_t)N_TOT * 8);
    unsigned short* Wt1    = (unsigned short*)alloc((size_t)D * D * 2);
    unsigned short* Wt2    = (unsigned short*)alloc((size_t)D * D * 2);
    unsigned short* g      = (unsigned short*)alloc((size_t)MPAD * D * 2);
    unsigned short* h1     = (unsigned short*)alloc((size_t)MPAD * D * 2);

    hipMemsetAsync(cnt, 0, zero_span, stream);
    k1_kernel<<<(N_TOT + 255) / 256, 256, 0, stream>>>(ei, W1, W2, cnt, Wt1, Wt2);
    k2_kernel<<<SCAN_B, 256, 0, stream>>>(cnt, dis, locs, bsum, done);
    k3_kernel<<<(N_TOT + 255) / 256, 256, 0, stream>>>(ei, locs, bsum, dis, fc,
                                                       rowptr, epk);
    // layer 1: g = Agg(relu(x*We+be)) via per-edge recompute; h1 = relu(g*W1+b1)
    agg1r_kernel<<<MPAD / 4, 256, 0, stream>>>(x, We, be, rowptr, epk, g);
    gemm_kernel<<<GEMM_B, 256, 0, stream>>>(g, Wt1, b1, h1, nullptr, 1);
    // layer 2: g = Agg(h1); out = g*W2 + b2   (g buffer reused)
    agg2_kernel<<<(N_NODES + 3) / 4, 256, 0, stream>>>(h1, rowptr, epk, g);
    gemm_kernel<<<GEMM_B, 256, 0, stream>>>(g, Wt2, b2, nullptr, out, 0);
}

// Round 10
// 233.097 us; speedup vs baseline: 1.3162x; 1.1357x over previous
//
#include <hip/hip_runtime.h>

#define N_NODES 50000
#define N_EDGES 300000
#define N_TOT   350000   // edges + self-loops
#define D       256
#define MPAD    50048    // N_NODES padded to multiple of 128 for GEMM
#define SCAN_B  196      // ceil(50000/256)
#define GEMM_B  784      // 8 XCDs x 98 slots (covers 391 M-tiles x 2 N-halves)
#define EMAXB   192      // LDS edge-slice cap per 4-node block (mean 28, 31 sigma)

typedef __attribute__((ext_vector_type(8))) short bf16x8;
typedef __attribute__((ext_vector_type(4))) float f32x4;
typedef __attribute__((ext_vector_type(8))) unsigned short u16x8;
typedef __attribute__((ext_vector_type(4))) unsigned short u16x4;

__device__ __forceinline__ float bf2f(unsigned short b) {
    union { unsigned u; float f; } v; v.u = ((unsigned)b) << 16; return v.f;
}
__device__ __forceinline__ unsigned short f2bf(float f) {
    union { float f; unsigned u; } v; v.f = f;
    unsigned u = v.u;
    unsigned r = (u + 0x7FFFu + ((u >> 16) & 1u)) >> 16;   // round-nearest-even
    return (unsigned short)r;
}
__device__ __forceinline__ void g2lds16(const unsigned short* g, unsigned short* l) {
    __builtin_amdgcn_global_load_lds(
        (const __attribute__((address_space(1))) void*)g,
        (__attribute__((address_space(3))) void*)l, 16, 0, 0);
}

// ---- k1: hist + W-transpose + embed, all independent, grid = MPAD/8 = 6256 ----
__global__ __launch_bounds__(256) void k1_kernel(
        const float* __restrict__ x, const int* __restrict__ ei,
        const float* __restrict__ We, const float* __restrict__ be,
        const float* __restrict__ W1, const float* __restrict__ W2,
        int* __restrict__ cnt,
        unsigned short* __restrict__ Wt1, unsigned short* __restrict__ Wt2,
        unsigned short* __restrict__ hA) {
    int t = threadIdx.x, b = blockIdx.x;
    int tid = b * 256 + t;

    // histogram over dst (cnt pre-zeroed by memset)
    if (tid < N_TOT) {
        int dst = (tid < N_EDGES) ? ei[N_EDGES + tid] : (tid - N_EDGES);
        atomicAdd(&cnt[dst], 1);
    }
    // transpose + cast weights (first 512 blocks, 1 elem/thread)
    if (tid < 2 * D * D) {
        int wsel = tid >> 16, rem = tid & 65535;
        int tt = rem >> 8, bb = rem & 255;             // coalesced over bb
        const float* W = wsel ? W2 : W1;
        unsigned short* Wt = wsel ? Wt2 : Wt1;
        Wt[bb * D + tt] = f2bf(W[tt * D + bb]);
    }
    // embed: block b -> nodes b*8 .. b*8+7 (pad rows get 0)
    float w[11];
    #pragma unroll
    for (int k = 0; k < 11; ++k) w[k] = We[k * D + t];
    float bb = be[t];
    #pragma unroll
    for (int ni = 0; ni < 8; ++ni) {
        int node = b * 8 + ni;
        float acc = 0.f;
        if (node < N_NODES) {
            acc = bb;
            #pragma unroll
            for (int k = 0; k < 11; ++k) acc += x[node * 11 + k] * w[k];
            acc = fmaxf(acc, 0.f);
        }
        hA[(size_t)node * D + t] = f2bf(acc);
    }
}

// ---- k3: rowptr materialization + CSR fill (packed src+norm, one 8B store) ----
__global__ __launch_bounds__(256) void k3_kernel(const int* __restrict__ ei,
                          const int* __restrict__ locs,
                          const int* __restrict__ bsum, const float* __restrict__ dis,
                          int* __restrict__ fc, int* __restrict__ rowptr,
                          int2* __restrict__ epk) {
    int tid = blockIdx.x * 256 + threadIdx.x;
    if (tid == 0) rowptr[0] = 0;
    if (tid < N_NODES)
        rowptr[tid + 1] = locs[tid] + bsum[tid >> 8];
    if (tid < N_TOT) {
        int src, dst;
        if (tid < N_EDGES) { src = ei[tid]; dst = ei[N_EDGES + tid]; }
        else               { src = dst = tid - N_EDGES; }
        int base = bsum[dst >> 8] + ((dst & 255) ? locs[dst - 1] : 0);
        int pos = base + atomicAdd(&fc[dst], 1);
        epk[pos] = make_int2(src, __float_as_int(dis[src] * dis[dst]));
    }
}

// ---- GEMM v3 (r2-verified): BK=64, 1-D grid with chunked XCD mapping
// co-locating the (m, y=0)/(m, y=1) pair on one XCD; XOR-swizzled LDS
// (inverse swizzle on the GLOBAL source, rule both-sides-or-neither);
// swapped-operand MFMA epilogue (8B stores); k2 scan side-job. ----
__global__ __launch_bounds__(256) void gemm_kernel(const unsigned short* __restrict__ A,
                                                   const unsigned short* __restrict__ Bt,
                                                   unsigned short* __restrict__ C,
                                                   const int* __restrict__ cnt,
                                                   float* __restrict__ dis,
                                                   int* __restrict__ locs,
                                                   int* __restrict__ bsum,
                                                   int* __restrict__ done) {
    __shared__ unsigned short lA[128 * 64];   // 16KB
    __shared__ unsigned short lB[128 * 64];   // 16KB
    __shared__ int ws[4];
    __shared__ int amLast;
    int t = threadIdx.x;
    int bid = blockIdx.x;

    // chunked pair mapping: xcd = bid%8 (HW round-robin assumption; perf-only)
    int xcd = bid & 7, s = bid >> 3;
    int pair = xcd * 49 + (s >> 1);           // M-tile
    int ny   = s & 1;                         // N-half
    if (pair >= MPAD / 128) return;           // bids 775/783 only; never scan blocks

    // ---- side job: k2 scan (only when cnt != nullptr), blocks bid<196 ----
    if (cnt && bid < SCAN_B) {
        int lane = t & 63, wv4 = t >> 6;
        int i = bid * 256 + t;
        int v = (i < N_NODES) ? cnt[i] : 0;
        if (i < N_NODES) dis[i] = rsqrtf((float)v);    // deg >= 1 (self-loop)
        int ssum = v;
        #pragma unroll
        for (int d = 1; d < 64; d <<= 1) {
            int u = __shfl_up(ssum, d, 64);
            if (lane >= d) ssum += u;
        }
        if (lane == 63) ws[wv4] = ssum;
        __syncthreads();
        int off = 0;
        #pragma unroll
        for (int k = 0; k < 4; ++k) if (k < wv4) off += ws[k];
        ssum += off;
        if (i < N_NODES) locs[i] = ssum;               // inclusive local scan
        if (t == 255) {
            bsum[bid] = ssum;
            __threadfence();
            amLast = (atomicAdd(done, 1) == SCAN_B - 1);
        }
        __syncthreads();
        if (amLast) {
            __threadfence();
            int vv = 0;
            if (t < SCAN_B)
                vv = __hip_atomic_load(&bsum[t], __ATOMIC_RELAXED, __HIP_MEMORY_SCOPE_AGENT);
        int ss = vv;
            #pragma unroll
            for (int d = 1; d < 64; d <<= 1) {
                int u = __shfl_up(ss, d, 64);
                if (lane >= d) ss += u;
            }
            __syncthreads();                           // ws reuse
            if (lane == 63) ws[wv4] = ss;
            __syncthreads();
            int off2 = 0;
            #pragma unroll
            for (int k = 0; k < 4; ++k) if (k < wv4) off2 += ws[k];
            ss += off2;
            if (t < SCAN_B) bsum[t] = ss - vv;         // exclusive block offsets
        }
        __syncthreads();
    }

    // ---- GEMM body ----
    int wv = t >> 6, lane = t & 63;
    int m0 = pair * 128;
    int n0 = ny * 128;
    int moff = (wv & 1) * 64, noff = (wv >> 1) * 64;
    int q = lane >> 4, r = lane & 15;

    // staging: 4 chunks/thread/tile; idx = j*256+t -> row=idx>>3, slot=idx&7,
    // source chunk c = slot ^ (row&7)
    int srow[4], scol[4];
    #pragma unroll
    for (int j = 0; j < 4; ++j) {
        int idx = j * 256 + t;
        srow[j] = idx >> 3;
        scol[j] = ((idx & 7) ^ (srow[j] & 7)) * 8;
    }

    f32x4 acc[4][4] = {};
    for (int kk = 0; kk < D; kk += 64) {
        __syncthreads();
        #pragma unroll
        for (int j = 0; j < 4; ++j) {
            int idx = j * 256 + t;
            g2lds16(A  + (size_t)(m0 + srow[j]) * D + kk + scol[j], lA + idx * 8);
            g2lds16(Bt + (size_t)(n0 + srow[j]) * D + kk + scol[j], lB + idx * 8);
        }
        __syncthreads();
        #pragma unroll
        for (int ks = 0; ks < 2; ++ks) {
            bf16x8 a[4], b[4];
            #pragma unroll
            for (int mt = 0; mt < 4; ++mt) {
                int row = moff + mt * 16 + r;
                a[mt] = *(const bf16x8*)(lA + row * 64 + (((ks * 4 + q) ^ (r & 7)) * 8));
            }
            #pragma unroll
            for (int nt = 0; nt < 4; ++nt) {
                int row = noff + nt * 16 + r;
                b[nt] = *(const bf16x8*)(lB + row * 64 + (((ks * 4 + q) ^ (r & 7)) * 8));
            }
            #pragma unroll
            for (int mt = 0; mt < 4; ++mt)
                #pragma unroll
                for (int nt = 0; nt < 4; ++nt)
                    acc[mt][nt] = __builtin_amdgcn_mfma_f32_16x16x32_bf16(b[nt], a[mt], acc[mt][nt], 0, 0, 0);
        }
    }
    #pragma unroll
    for (int mt = 0; mt < 4; ++mt) {
        int mrow = m0 + moff + mt * 16 + r;
        #pragma unroll
        for (int nt = 0; nt < 4; ++nt) {
            int ncol = n0 + noff + nt * 16 + (q << 2);
            u16x4 o;
            #pragma unroll
            for (int i = 0; i < 4; ++i) o[i] = f2bf(acc[mt][nt][i]);
            *(u16x4*)(C + (size_t)mrow * D + ncol) = o;
        }
    }
}

// ---- agg v8: wave per node, 8 rows in flight via half-waves (as v7), but
// the block's 4-node CSR slice is CONTIGUOUS -> stage it to LDS once and
// broadcast-read edge records (conflict-free same-address LDS reads),
// replacing the v7 shfl(ds_bpermute) redistribution + wrap arithmetic.
// Tail over-issue: clamp index, zero norm (row re-read is L2-hot). ----
__global__ __launch_bounds__(256) void agg_kernel(const unsigned short* __restrict__ hw,
                                                  const int* __restrict__ rowptr,
                                                  const int2* __restrict__ epk,
                                                  const float* __restrict__ bias,
                                                  unsigned short* __restrict__ out_bf,
                                                  float* __restrict__ out_f32,
                                                  int mode) {
    __shared__ int2 eS[EMAXB];
    __shared__ int rS[5];
    int t = threadIdx.x;
    int nb = blockIdx.x * 4;                       // nb+4 <= 50000 always
    if (t <= 4) rS[t] = rowptr[nb + t];
    __syncthreads();
    int s0b = rS[0];
    int nE = rS[4] - s0b;
    bool useL = (nE <= EMAXB);                     // block-uniform
    if (useL)
        for (int i = t; i < nE; i += 256) eS[i] = epk[s0b + i];
    __syncthreads();

    int wid = t >> 6, lane = t & 63;
    int node = nb + wid;
    int half = lane >> 5, hl = lane & 31;
    int gb  = rS[wid];                             // global CSR base for my node
    int ls  = gb - s0b;                            // LDS-local base
    int deg = rS[wid + 1] - gb;                    // >= 1 (self-loop)
    int dm  = deg - 1;

    float acc[8] = {};
    for (int c = 0; c < deg; c += 8) {             // 8 edges per chunk (4/half)
        int e0 = c + half,     e1 = c + 2 + half;
        int e2 = c + 4 + half, e3 = c + 6 + half;
        int f0 = e0 > dm ? dm : e0, f1 = e1 > dm ? dm : e1;
        int f2 = e2 > dm ? dm : e2, f3 = e3 > dm ? dm : e3;
        int2 p0 = useL ? eS[ls + f0] : epk[gb + f0];
        int2 p1 = useL ? eS[ls + f1] : epk[gb + f1];
        int2 p2 = useL ? eS[ls + f2] : epk[gb + f2];
        int2 p3 = useL ? eS[ls + f3] : epk[gb + f3];
        float n0 = (e0 <= dm) ? __int_as_float(p0.y) : 0.f;
        float n1 = (e1 <= dm) ? __int_as_float(p1.y) : 0.f;
        float n2 = (e2 <= dm) ? __int_as_float(p2.y) : 0.f;
        float n3 = (e3 <= dm) ? __int_as_float(p3.y) : 0.f;
        u16x8 r0 = *(const u16x8*)(hw + (size_t)p0.x * D + hl * 8);
        u16x8 r1 = *(const u16x8*)(hw + (size_t)p1.x * D + hl * 8);
        u16x8 r2 = *(const u16x8*)(hw + (size_t)p2.x * D + hl * 8);
        u16x8 r3 = *(const u16x8*)(hw + (size_t)p3.x * D + hl * 8);
        #pragma unroll
        for (int k = 0; k < 8; ++k) acc[k] += n0 * bf2f(r0[k]);
        #pragma unroll
        for (int k = 0; k < 8; ++k) acc[k] += n1 * bf2f(r1[k]);
        #pragma unroll
        for (int k = 0; k < 8; ++k) acc[k] += n2 * bf2f(r2[k]);
        #pragma unroll
        for (int k = 0; k < 8; ++k) acc[k] += n3 * bf2f(r3[k]);
    }
    #pragma unroll
    for (int k = 0; k < 8; ++k) acc[k] += __shfl_xor(acc[k], 32, 64);

    if (lane < 32) {
        int c = hl * 8;
        float4 bv0 = *(const float4*)(bias + c);
        float4 bv1 = *(const float4*)(bias + c + 4);
        float v[8];
        v[0] = acc[0] + bv0.x; v[1] = acc[1] + bv0.y;
        v[2] = acc[2] + bv0.z; v[3] = acc[3] + bv0.w;
        v[4] = acc[4] + bv1.x; v[5] = acc[5] + bv1.y;
        v[6] = acc[6] + bv1.z; v[7] = acc[7] + bv1.w;
        if (mode) {
            u16x8 ov;
            #pragma unroll
            for (int k = 0; k < 8; ++k) ov[k] = f2bf(fmaxf(v[k], 0.f));
            *(u16x8*)(out_bf + (size_t)node * D + c) = ov;
        } else {
            float4 o0 = { v[0], v[1], v[2], v[3] };
            float4 o1 = { v[4], v[5], v[6], v[7] };
            *(float4*)(out_f32 + (size_t)node * D + c)     = o0;
            *(float4*)(out_f32 + (size_t)node * D + c + 4) = o1;
        }
    }
}

extern "C" void kernel_launch(void* const* d_in, const int* in_sizes, int n_in,
                              void* d_out, int out_size, void* d_ws, size_t ws_size,
                              hipStream_t stream) {
    const float* x  = (const float*)d_in[0];
    const int*   ei = (const int*)d_in[1];
    const float* We = (const float*)d_in[2];
    const float* be = (const float*)d_in[3];
    const float* W1 = (const float*)d_in[4];
    const float* b1 = (const float*)d_in[5];
    const float* W2 = (const float*)d_in[6];
    const float* b2 = (const float*)d_in[7];
    float* out = (float*)d_out;

    char* w = (char*)d_ws;
    auto alloc = [&](size_t bytes) {
        char* p = w;
        w += (bytes + 255) & ~(size_t)255;
        return p;
    };
    // cnt, fc, done contiguous -> single memset covers all three
    int*            cnt    = (int*)alloc((size_t)N_NODES * 4);
    int*            fc     = (int*)alloc((size_t)N_NODES * 4);
    int*            done   = (int*)alloc(4);
    size_t zero_span = (size_t)((char*)(done + 64) - (char*)cnt);
    int*            rowptr = (int*)alloc((size_t)(N_NODES + 1) * 4);
    int*            locs   = (int*)alloc((size_t)N_NODES * 4);
    int*            bsum   = (int*)alloc((size_t)SCAN_B * 4);
    float*          dis    = (float*)alloc((size_t)N_NODES * 4);
    int2*           epk    = (int2*)alloc((size_t)N_TOT * 8);
    unsigned short* Wt1    = (unsigned short*)alloc((size_t)D * D * 2);
    unsigned short* Wt2    = (unsigned short*)alloc((size_t)D * D * 2);
    unsigned short* hA     = (unsigned short*)alloc((size_t)MPAD * D * 2);
    unsigned short* hW     = (unsigned short*)alloc((size_t)MPAD * D * 2);

    hipMemsetAsync(cnt, 0, zero_span, stream);
    k1_kernel<<<MPAD / 8, 256, 0, stream>>>(x, ei, We, be, W1, W2, cnt, Wt1, Wt2, hA);

    // gemm1 carries the k2 scan side-job (needs only k1's cnt)
    gemm_kernel<<<GEMM_B, 256, 0, stream>>>(hA, Wt1, hW, cnt, dis, locs, bsum, done);
    k3_kernel<<<(N_TOT + 255) / 256, 256, 0, stream>>>(ei, locs, bsum, dis, fc,
                                                       rowptr, epk);
    agg_kernel<<<(N_NODES + 3) / 4, 256, 0, stream>>>(hW, rowptr, epk, b1,
                                                      hA, nullptr, 1);

    gemm_kernel<<<GEMM_B, 256, 0, stream>>>(hA, Wt2, hW, nullptr, nullptr, nullptr,
                                            nullptr, nullptr);
    agg_kernel<<<(N_NODES + 3) / 4, 256, 0, stream>>>(hW, rowptr, epk, b2,
                                                      nullptr, out, 0);
}